// Round 1
// baseline (852.170 us; speedup 1.0000x reference)
//
#include <hip/hip_runtime.h>
#include <hip/hip_bf16.h>

// Problem constants
// B=32, N=64, D=30, ND=64, F0=64, H1=128, H2=64, H3=32, L=8, SINK_K=10
// LAMDA = {0.01,0.1,0.5,1.0,3.0,5.0,10.0,20.0}, P0=0.5, EPS=1e-6

__device__ __constant__ float c_LAM[8] = {0.01f, 0.1f, 0.5f, 1.0f, 3.0f, 5.0f, 10.0f, 20.0f};

// ---------------- workspace layout (float offsets) ----------------
constexpr int OFF_XE   = 0;         // 32*64*32 = 65536
constexpr int OFF_DE   = 65536;     // 30*64*32 = 61440
constexpr int OFF_DS   = 126976;    // 30*64*32 = 61440
constexpr int OFF_X2   = 188416;    // 2048
constexpr int OFF_Y2   = 190464;    // 1920
constexpr int OFF_Z    = 192384;    // 32
constexpr int OFF_C0   = 192416;    // 16
constexpr int OFF_KL   = 192432;    // 48
constexpr int OFF_GALL = 192480;    // 8*32*960 = 245760
constexpr int OFF_WBUF = 438272;    // 7680*4096 = 31457280  (two-phase only)
constexpr size_t WS_NEED_TWO_PHASE = (size_t)(OFF_WBUF + 7680ull * 4096ull) * 4ull; // 127,582,208 B

// =====================================================================
// GCN encoder: one block per graph (blocks 0..31 = x-encoder, 32..61 = dict)
// Register-tiled 4x4 small matmul helper. A is read scalar (broadcast),
// W is read as float4 rows, C written as float4.
// =====================================================================
template <int K, int J>
__device__ __forceinline__ void mm64(const float* __restrict__ A, int lda,
                                     const float* __restrict__ W,
                                     float* __restrict__ C,
                                     const float* __restrict__ bias,
                                     bool do_relu, int t) {
  constexpr int JT = J >> 2;        // float4 tiles per row
  constexpr int TILES = 16 * JT;    // 16 i-tiles (64 rows / 4)
  for (int task = t; task < TILES; task += 256) {
    int i4 = task / JT;
    int j4 = task - i4 * JT;
    const float* a0 = A + (i4 * 4 + 0) * lda;
    const float* a1 = a0 + lda;
    const float* a2 = a1 + lda;
    const float* a3 = a2 + lda;
    float acc[4][4];
#pragma unroll
    for (int r = 0; r < 4; ++r)
#pragma unroll
      for (int c = 0; c < 4; ++c) acc[r][c] = 0.0f;
    const float* wp = W + j4 * 4;
#pragma unroll 8
    for (int k = 0; k < K; ++k) {
      float4 w = *(const float4*)(wp + k * J);
      float v0 = a0[k], v1 = a1[k], v2 = a2[k], v3 = a3[k];
      acc[0][0] += v0 * w.x; acc[0][1] += v0 * w.y; acc[0][2] += v0 * w.z; acc[0][3] += v0 * w.w;
      acc[1][0] += v1 * w.x; acc[1][1] += v1 * w.y; acc[1][2] += v1 * w.z; acc[1][3] += v1 * w.w;
      acc[2][0] += v2 * w.x; acc[2][1] += v2 * w.y; acc[2][2] += v2 * w.z; acc[2][3] += v2 * w.w;
      acc[3][0] += v3 * w.x; acc[3][1] += v3 * w.y; acc[3][2] += v3 * w.z; acc[3][3] += v3 * w.w;
    }
    float4 bv = make_float4(0.f, 0.f, 0.f, 0.f);
    if (bias) bv = *(const float4*)(bias + j4 * 4);
#pragma unroll
    for (int r = 0; r < 4; ++r) {
      float o0 = acc[r][0] + bv.x, o1 = acc[r][1] + bv.y;
      float o2 = acc[r][2] + bv.z, o3 = acc[r][3] + bv.w;
      if (do_relu) {
        o0 = fmaxf(o0, 0.f); o1 = fmaxf(o1, 0.f);
        o2 = fmaxf(o2, 0.f); o3 = fmaxf(o3, 0.f);
      }
      float4 st = make_float4(o0, o1, o2, o3);
      *(float4*)(C + (i4 * 4 + r) * J + j4 * 4) = st;
    }
  }
}

__global__ __launch_bounds__(256) void gcn_kernel(
    const float* __restrict__ x, const float* __restrict__ adj,
    const float* __restrict__ eW1, const float* __restrict__ eb1,
    const float* __restrict__ eW2, const float* __restrict__ eb2,
    const float* __restrict__ eW3, const float* __restrict__ eb3,
    const float* __restrict__ dx, const float* __restrict__ dadj,
    const float* __restrict__ dW1, const float* __restrict__ db1,
    const float* __restrict__ dW2, const float* __restrict__ db2,
    const float* __restrict__ dW3, const float* __restrict__ db3,
    float* __restrict__ xe, float* __restrict__ de) {
  __shared__ __align__(16) float C0[64 * 128];
  __shared__ __align__(16) float C1[64 * 128];
  int t = threadIdx.x;
  const float *src, *ad, *W1, *b1, *W2, *b2, *W3, *b3;
  float* outp;
  if (blockIdx.x < 32) {
    int g = blockIdx.x;
    src = x + g * 4096; ad = adj + g * 4096;
    W1 = eW1; b1 = eb1; W2 = eW2; b2 = eb2; W3 = eW3; b3 = eb3;
    outp = xe + g * 2048;
  } else {
    int g = blockIdx.x - 32;
    src = dx + g * 4096; ad = dadj + g * 4096;
    W1 = dW1; b1 = db1; W2 = dW2; b2 = db2; W3 = dW3; b3 = db3;
    outp = de + g * 2048;
  }
  // T1 = x @ W1 : (64xF0)@(F0x128)
  mm64<64, 128>(src, 64, W1, C1, nullptr, false, t);
  __syncthreads();
  // H1 = relu(adj @ T1 + b1)
  mm64<64, 128>(ad, 64, C1, C0, b1, true, t);
  __syncthreads();
  // T2 = H1 @ W2 : (64x128)@(128x64)
  mm64<128, 64>(C0, 128, W2, C1, nullptr, false, t);
  __syncthreads();
  // H2 = relu(adj @ T2 + b2)
  mm64<64, 64>(ad, 64, C1, C0, b2, true, t);
  __syncthreads();
  // T3 = H2 @ W3 : (64x64)@(64x32)
  mm64<64, 32>(C0, 64, W3, C1, nullptr, false, t);
  __syncthreads();
  // enc = adj @ T3 + b3 -> global
  mm64<64, 32>(ad, 64, C1, outp, b3, false, t);
}

// =====================================================================
// x2[b,n] = sum_f x_enc^2
// =====================================================================
__global__ __launch_bounds__(256) void x2_kernel(const float* __restrict__ xe,
                                                 float* __restrict__ x2) {
  int i = blockIdx.x * 256 + threadIdx.x;  // < 2048
  const float* r = xe + i * 32;
  float s = 0.f;
#pragma unroll
  for (int f = 0; f < 32; ++f) s += r[f] * r[f];
  x2[i] = s;
}

// =====================================================================
// Folded attention MLP: z[f] = sum_b mlp2_w[b] * sum_n mlp_w[n]*yn[b,n,f]
// c0 = mlp_b * sum_b mlp2_w[b] + mlp2_b
// yn normalized over nodes (axis N) per (b, f).
// =====================================================================
__global__ __launch_bounds__(256) void z_kernel(
    const float* __restrict__ xe, const float* __restrict__ mlp_w,
    const float* __restrict__ mlp_b, const float* __restrict__ mlp2_w,
    const float* __restrict__ mlp2_b, float* __restrict__ z,
    float* __restrict__ c0) {
  __shared__ float yb[32 * 33];
  int t = threadIdx.x;
  for (int idx = t; idx < 1024; idx += 256) {
    int b = idx >> 5, f = idx & 31;
    float s = 0.f, sb = 0.f;
    for (int n = 0; n < 64; ++n) {
      float v = xe[b * 2048 + n * 32 + f];
      s += v * v;
      sb += v * mlp_w[n];
    }
    yb[b * 33 + f] = sb / (sqrtf(s) + 1e-12f);
  }
  __syncthreads();
  if (t < 32) {
    float zz = 0.f;
    for (int b = 0; b < 32; ++b) zz += yb[b * 33 + t] * mlp2_w[b];
    z[t] = zz;
    if (t == 0) {
      float sm2 = 0.f;
      for (int b = 0; b < 32; ++b) sm2 += mlp2_w[b];
      c0[0] = mlp_b[0] * sm2 + mlp2_b[0];
    }
  }
}

// =====================================================================
// JAX threefry2x32, key = (0, 42) (jax.random.key(42))
// =====================================================================
__device__ __forceinline__ unsigned rotl32(unsigned v, int s) {
  return (v << s) | (v >> (32 - s));
}
__device__ __forceinline__ void threefry42(unsigned x0, unsigned x1,
                                           unsigned& o0, unsigned& o1) {
  const unsigned ks0 = 0u, ks1 = 42u, ks2 = 0x1BD11BDAu ^ 0u ^ 42u;
  unsigned ks[3] = {ks0, ks1, ks2};
  x0 += ks[0];
  x1 += ks[1];
  const int R[2][4] = {{13, 15, 26, 6}, {17, 29, 16, 24}};
#pragma unroll
  for (int r = 0; r < 5; ++r) {
    const int* rr = R[r & 1];
#pragma unroll
    for (int i = 0; i < 4; ++i) {
      x0 += x1;
      x1 = rotl32(x1, rr[i]);
      x1 ^= x0;
    }
    x0 += ks[(r + 1) % 3];
    x1 += ks[(r + 2) % 3] + (unsigned)(r + 1);
  }
  o0 = x0;
  o1 = x1;
}

// =====================================================================
// attn (sigmoid of folded MLP), bernoulli sample, d_samp, y2, kl partials
// grid = 30 (d), block = 64 (m)
// =====================================================================
__global__ __launch_bounds__(64) void attn_kernel(
    const float* __restrict__ de, const float* __restrict__ z,
    const float* __restrict__ c0, float* __restrict__ dsamp,
    float* __restrict__ y2, float* __restrict__ klpart) {
  int d = blockIdx.x, m = threadIdx.x;
  __shared__ float dn[32];
  if (m < 32) {
    float s = 0.f;
    for (int n = 0; n < 64; ++n) {
      float v = de[d * 2048 + n * 32 + m];
      s += v * v;
    }
    dn[m] = sqrtf(s) + 1e-12f;
  }
  __syncthreads();
  const float* row = de + d * 2048 + m * 32;
  float logit = c0[0], s2 = 0.f;
#pragma unroll 8
  for (int f = 0; f < 32; ++f) {
    float v = row[f];
    logit += (v / dn[f]) * z[f];
    s2 += v * v;
  }
  float attn = 1.0f / (1.0f + expf(-logit));
  int e = d * 64 + m;
  unsigned o0, o1, bits;
  if (e < 960) {
    threefry42((unsigned)e, (unsigned)(960 + e), o0, o1);
    bits = o0;
  } else {
    threefry42((unsigned)(e - 960), (unsigned)e, o0, o1);
    bits = o1;
  }
  float u = __uint_as_float((bits >> 9) | 0x3f800000u) - 1.0f;
  u = fmaxf(u, 0.0f);
  float bern = (u < attn) ? 1.0f : 0.0f;
  float* dr = dsamp + d * 2048 + m * 32;
#pragma unroll 8
  for (int f = 0; f < 32; ++f) dr[f] = bern * row[f];
  y2[e] = bern * s2;
  float klt = attn * logf(2.0f * attn) + (1.0f - attn) * logf(2.0f * (1.0f - attn));
#pragma unroll
  for (int off = 32; off > 0; off >>= 1) klt += __shfl_down(klt, off, 64);
  if (m == 0) klpart[d] = klt;
}

// =====================================================================
// Fused M / exp / Sinkhorn(10) / G-normalize per (b,d) block, 8 lambdas.
// TWO_PHASE=1: writes W = Ghat*M rows to Wbuf (gd GEMM done separately)
// TWO_PHASE=0: fused gd GEMV against dist_para (global), writes gall
// =====================================================================
template <int TWO_PHASE>
__global__ __launch_bounds__(256) void sink_kernel(
    const float* __restrict__ xe, const float* __restrict__ ds,
    const float* __restrict__ x2g, const float* __restrict__ y2g,
    const int* __restrict__ num_node, const int* __restrict__ dict_nnode,
    const float* __restrict__ dp, float* __restrict__ outbuf) {
  constexpr int O_ML = 0;            // 64*65 = 4160
  constexpr int O_KM = 4160;         // 64*67 = 4288 (aliases XE/DS below)
  constexpr int O_XE = 4160;         // 64*33 = 2112
  constexpr int O_DSL = 4160 + 2112; // 64*33 = 2112
  constexpr int O_UI = 8448;
  constexpr int O_VI = 8512;
  constexpr int O_W1 = 8576;
  constexpr int O_W2 = 8640;
  constexpr int O_X2 = 8704;
  constexpr int O_Y2 = 8768;
  constexpr int O_RMIN = 8832;
  constexpr int O_RINV = 8896;
  constexpr int O_SCR = 8960;        // 1056
  __shared__ __align__(16) float sm[10016];
  float* ML = sm + O_ML;
  float* KM = sm + O_KM;

  int t = threadIdx.x;
  int b = blockIdx.x / 30;
  int d = blockIdx.x - b * 30;

  {
    const float* xsrc = xe + b * 2048;
    const float* dsrc = ds + d * 2048;
    for (int i = t; i < 2048; i += 256) {
      int r = i >> 5, c = i & 31;
      sm[O_XE + r * 33 + c] = xsrc[i];
      sm[O_DSL + r * 33 + c] = dsrc[i];
    }
  }
  if (t < 64) {
    int nn = num_node[b], dnn = dict_nnode[d];
    sm[O_W1 + t] = (t < nn) ? 1.0f / (float)nn : 0.0f;
    sm[O_W2 + t] = (t < dnn) ? 1.0f / (float)dnn : 0.0f;
    sm[O_X2 + t] = x2g[b * 64 + t];
    sm[O_Y2 + t] = y2g[d * 64 + t];
  }
  __syncthreads();
  // M[i][j] = x2[i] + y2[j] - 2 * <xe_i, ds_j>
  for (int idx = t; idx < 4096; idx += 256) {
    int i = idx >> 6, j = idx & 63;
    const float* xr = sm + O_XE + i * 33;
    const float* dr = sm + O_DSL + j * 33;
    float acc = 0.f;
#pragma unroll
    for (int f = 0; f < 32; ++f) acc += xr[f] * dr[f];
    ML[i * 65 + j] = sm[O_X2 + i] + sm[O_Y2 + j] - 2.0f * acc;
  }
  __syncthreads();

  const int m_ = t & 63;
  const int q_ = t >> 6;

  for (int l = 0; l < 8; ++l) {
    float lam = c_LAM[l];
    // Km = exp(-lam*M) * mask   (overwrites xe/ds alias region)
    for (int idx = t; idx < 4096; idx += 256) {
      int i = idx >> 6, j = idx & 63;
      float kv = 0.0f;
      if (sm[O_W1 + i] > 0.0f && sm[O_W2 + j] > 0.0f)
        kv = __expf(-lam * ML[i * 65 + j]);
      KM[i * 67 + j] = kv;
    }
    if (t < 64) sm[O_UI + t] = 1.0f;
    __syncthreads();

    // register fragments: column chunk (rows q*16.. for column m_) and
    // transposed row chunk (row m_, cols q*16..)
    float kreg[16], kregT[16];
#pragma unroll
    for (int nn = 0; nn < 16; ++nn) {
      kreg[nn] = KM[(q_ * 16 + nn) * 67 + m_];
      kregT[nn] = KM[m_ * 67 + q_ * 16 + nn];
    }

    for (int it = 0; it < 10; ++it) {
      {
        float s = 0.f;
#pragma unroll
        for (int nn = 0; nn < 16; ++nn) s += kreg[nn] * sm[O_UI + q_ * 16 + nn];
        sm[O_SCR + t] = s;
      }
      __syncthreads();
      if (t < 64) {
        float tv = sm[O_SCR + t] + sm[O_SCR + 64 + t] + sm[O_SCR + 128 + t] +
                   sm[O_SCR + 192 + t];
        sm[O_VI + t] = sm[O_W2 + t] / (tv + 1e-6f);
      }
      __syncthreads();
      {
        float s = 0.f;
#pragma unroll
        for (int nn = 0; nn < 16; ++nn) s += kregT[nn] * sm[O_VI + q_ * 16 + nn];
        sm[O_SCR + t] = s;
      }
      __syncthreads();
      if (t < 64) {
        float tu = sm[O_SCR + t] + sm[O_SCR + 64 + t] + sm[O_SCR + 128 + t] +
                   sm[O_SCR + 192 + t];
        sm[O_UI + t] = sm[O_W1 + t] / (tu + 1e-6f);
      }
      __syncthreads();
    }

    // row-wise min/max of G = ui * Km * vi
    {
      float uin = sm[O_UI + m_];
      float mx = -3.402823466e38f, mn = 3.402823466e38f;
#pragma unroll
      for (int nn = 0; nn < 16; ++nn) {
        float g = uin * kregT[nn] * sm[O_VI + q_ * 16 + nn];
        mx = fmaxf(mx, g);
        mn = fminf(mn, g);
      }
      sm[O_SCR + t] = mx;
      sm[O_SCR + 512 + t] = mn;
    }
    __syncthreads();
    if (t < 64) {
      float mx = fmaxf(fmaxf(sm[O_SCR + t], sm[O_SCR + 64 + t]),
                       fmaxf(sm[O_SCR + 128 + t], sm[O_SCR + 192 + t]));
      float mn = fminf(fminf(sm[O_SCR + 512 + t], sm[O_SCR + 576 + t]),
                       fminf(sm[O_SCR + 640 + t], sm[O_SCR + 704 + t]));
      sm[O_RMIN + t] = mn;
      sm[O_RINV + t] = 1.0f / (mx - mn + 1e-6f);
    }
    __syncthreads();

    int row = (l * 32 + b) * 30 + d;
    if (TWO_PHASE) {
      float* wrow = outbuf + (size_t)row * 4096;
      for (int idx = t; idx < 4096; idx += 256) {
        int i = idx >> 6, j = idx & 63;
        float g = sm[O_UI + i] * KM[i * 67 + j] * sm[O_VI + j];
        float gh = (g - sm[O_RMIN + i]) * sm[O_RINV + i];
        wrow[idx] = gh * ML[i * 65 + j];
      }
      __syncthreads();
    } else {
      // overwrite KM with W = Ghat * M
      for (int idx = t; idx < 4096; idx += 256) {
        int i = idx >> 6, j = idx & 63;
        float g = sm[O_UI + i] * KM[i * 67 + j] * sm[O_VI + j];
        float gh = (g - sm[O_RMIN + i]) * sm[O_RINV + i];
        KM[i * 67 + j] = gh * ML[i * 65 + j];
      }
      __syncthreads();
      // gd[k] = sum_p W[p] * dp[p][k]
      {
        int k4 = t & 7, q = t >> 3;
        const float4* dp4 = (const float4*)dp;
        float4 acc = make_float4(0.f, 0.f, 0.f, 0.f);
        int p0 = q * 128;
        for (int pp = 0; pp < 128; ++pp) {
          int p = p0 + pp;
          float w = KM[(p >> 6) * 67 + (p & 63)];
          float4 dv = dp4[p * 8 + k4];
          acc.x += w * dv.x;
          acc.y += w * dv.y;
          acc.z += w * dv.z;
          acc.w += w * dv.w;
        }
        sm[O_SCR + (k4 * 4 + 0) * 33 + q] = acc.x;
        sm[O_SCR + (k4 * 4 + 1) * 33 + q] = acc.y;
        sm[O_SCR + (k4 * 4 + 2) * 33 + q] = acc.z;
        sm[O_SCR + (k4 * 4 + 3) * 33 + q] = acc.w;
      }
      __syncthreads();
      if (t < 32) {
        float s = 0.f;
#pragma unroll
        for (int q2 = 0; q2 < 32; ++q2) s += sm[O_SCR + t * 33 + q2];
        outbuf[(size_t)row * 32 + t] = s;
      }
      __syncthreads();
    }
  }
}

// =====================================================================
// Phase 2: gall(7680x32) = Wbuf(7680x4096) @ dp(4096x32)
// 64 threads per block; thread = 4 rows x 8 cols registers; 64 rows/block
// =====================================================================
__global__ __launch_bounds__(64) void gd_gemm_kernel(
    const float* __restrict__ Wbuf, const float* __restrict__ dp,
    float* __restrict__ gall) {
  __shared__ __align__(16) float WL[64 * 129];
  __shared__ __align__(16) float dpL[128 * 36];
  int t = threadIdx.x;
  int r0 = blockIdx.x << 6;
  int rt = t >> 2, kg = t & 3;
  float4 aA[4], aB[4];
#pragma unroll
  for (int r = 0; r < 4; ++r) {
    aA[r] = make_float4(0.f, 0.f, 0.f, 0.f);
    aB[r] = make_float4(0.f, 0.f, 0.f, 0.f);
  }
  for (int kk = 0; kk < 4096; kk += 128) {
    __syncthreads();
    for (int idx = t; idx < 8192; idx += 64) {
      int rr = idx >> 7, cc = idx & 127;
      WL[rr * 129 + cc] = Wbuf[(size_t)(r0 + rr) * 4096 + kk + cc];
    }
    for (int idx = t; idx < 4096; idx += 64) {
      int pp = idx >> 5, cc = idx & 31;
      dpL[pp * 36 + cc] = dp[(kk + pp) * 32 + cc];
    }
    __syncthreads();
    const float* w0p = WL + (rt * 4 + 0) * 129;
    const float* w1p = w0p + 129;
    const float* w2p = w1p + 129;
    const float* w3p = w2p + 129;
#pragma unroll 4
    for (int c = 0; c < 128; ++c) {
      const float* dvp = dpL + c * 36 + kg * 8;
      float4 d0 = *(const float4*)dvp;
      float4 d1 = *(const float4*)(dvp + 4);
      float w;
      w = w0p[c];
      aA[0].x += w * d0.x; aA[0].y += w * d0.y; aA[0].z += w * d0.z; aA[0].w += w * d0.w;
      aB[0].x += w * d1.x; aB[0].y += w * d1.y; aB[0].z += w * d1.z; aB[0].w += w * d1.w;
      w = w1p[c];
      aA[1].x += w * d0.x; aA[1].y += w * d0.y; aA[1].z += w * d0.z; aA[1].w += w * d0.w;
      aB[1].x += w * d1.x; aB[1].y += w * d1.y; aB[1].z += w * d1.z; aB[1].w += w * d1.w;
      w = w2p[c];
      aA[2].x += w * d0.x; aA[2].y += w * d0.y; aA[2].z += w * d0.z; aA[2].w += w * d0.w;
      aB[2].x += w * d1.x; aB[2].y += w * d1.y; aB[2].z += w * d1.z; aB[2].w += w * d1.w;
      w = w3p[c];
      aA[3].x += w * d0.x; aA[3].y += w * d0.y; aA[3].z += w * d0.z; aA[3].w += w * d0.w;
      aB[3].x += w * d1.x; aB[3].y += w * d1.y; aB[3].z += w * d1.z; aB[3].w += w * d1.w;
    }
  }
#pragma unroll
  for (int r = 0; r < 4; ++r) {
    size_t row = (size_t)(r0 + rt * 4 + r);
    *(float4*)(gall + row * 32 + kg * 8) = aA[r];
    *(float4*)(gall + row * 32 + kg * 8 + 4) = aB[r];
  }
}

// =====================================================================
// Final: coeff = softmax_l(gall @ wl), embed, fc1, fc2, kl
// grid = 32 (b), block = 256
// =====================================================================
__global__ __launch_bounds__(256) void final_kernel(
    const float* __restrict__ gall, const float* __restrict__ wl,
    const float* __restrict__ fc1w, const float* __restrict__ fc1b,
    const float* __restrict__ fc2w, const float* __restrict__ fc2b,
    const float* __restrict__ klpart, float* __restrict__ out) {
  int b = blockIdx.x, t = threadIdx.x;
  __shared__ float embedL[960];
  __shared__ float sred[32];
  __shared__ float coeff[8];
  __shared__ float hL[64];
  float part[8] = {0, 0, 0, 0, 0, 0, 0, 0};
  for (int j = t; j < 960; j += 256) {
    float w = wl[j];
#pragma unroll
    for (int l = 0; l < 8; ++l) part[l] += gall[l * 30720 + b * 960 + j] * w;
  }
#pragma unroll
  for (int off = 32; off > 0; off >>= 1) {
#pragma unroll
    for (int l = 0; l < 8; ++l) part[l] += __shfl_down(part[l], off, 64);
  }
  int wv = t >> 6, lane = t & 63;
  if (lane == 0) {
#pragma unroll
    for (int l = 0; l < 8; ++l) sred[l * 4 + wv] = part[l];
  }
  __syncthreads();
  if (t == 0) {
    float s[8], mx = -3.402823466e38f;
#pragma unroll
    for (int l = 0; l < 8; ++l) {
      s[l] = sred[l * 4] + sred[l * 4 + 1] + sred[l * 4 + 2] + sred[l * 4 + 3];
      mx = fmaxf(mx, s[l]);
    }
    float se = 0.f;
#pragma unroll
    for (int l = 0; l < 8; ++l) {
      s[l] = expf(s[l] - mx);
      se += s[l];
    }
#pragma unroll
    for (int l = 0; l < 8; ++l) coeff[l] = s[l] / se;
  }
  __syncthreads();
  for (int j = t; j < 960; j += 256) {
    float e = 0.f;
#pragma unroll
    for (int l = 0; l < 8; ++l) e += gall[l * 30720 + b * 960 + j] * coeff[l];
    embedL[j] = e;
  }
  __syncthreads();
  if (t < 64) {
    float h = fc1b[t];
    for (int j = 0; j < 960; ++j) h += embedL[j] * fc1w[t * 960 + j];
    hL[t] = h;
  }
  __syncthreads();
  if (t < 3) {
    float o = fc2b[t];
#pragma unroll
    for (int j = 0; j < 64; ++j) o += hL[j] * fc2w[t * 64 + j];
    out[b * 3 + t] = o;
  }
  if (b == 0 && t == 4) {
    float kl = 0.f;
    for (int dd = 0; dd < 30; ++dd) kl += klpart[dd];
    out[96] = kl;
  }
}

// =====================================================================
extern "C" void kernel_launch(void* const* d_in, const int* in_sizes, int n_in,
                              void* d_out, int out_size, void* d_ws,
                              size_t ws_size, hipStream_t stream) {
  (void)in_sizes; (void)n_in; (void)out_size;
  const float* x = (const float*)d_in[0];
  const float* adj = (const float*)d_in[1];
  const int* num_node = (const int*)d_in[2];
  const float* dict_feat = (const float*)d_in[3];
  const float* dict_adj = (const float*)d_in[4];
  const int* dict_nnode = (const int*)d_in[5];
  const float* eW1 = (const float*)d_in[6];
  const float* eb1 = (const float*)d_in[7];
  const float* eW2 = (const float*)d_in[8];
  const float* eb2 = (const float*)d_in[9];
  const float* eW3 = (const float*)d_in[10];
  const float* eb3 = (const float*)d_in[11];
  const float* dW1 = (const float*)d_in[12];
  const float* db1 = (const float*)d_in[13];
  const float* dW2 = (const float*)d_in[14];
  const float* db2 = (const float*)d_in[15];
  const float* dW3 = (const float*)d_in[16];
  const float* db3 = (const float*)d_in[17];
  const float* mlp_w = (const float*)d_in[18];
  const float* mlp_b = (const float*)d_in[19];
  const float* mlp2_w = (const float*)d_in[20];
  const float* mlp2_b = (const float*)d_in[21];
  const float* dist_para = (const float*)d_in[22];
  const float* weight_lamda = (const float*)d_in[23];
  const float* fc1_w = (const float*)d_in[24];
  const float* fc1_b = (const float*)d_in[25];
  const float* fc2_w = (const float*)d_in[26];
  const float* fc2_b = (const float*)d_in[27];

  float* ws = (float*)d_ws;
  float* xe = ws + OFF_XE;
  float* de = ws + OFF_DE;
  float* dsb = ws + OFF_DS;
  float* x2b = ws + OFF_X2;
  float* y2b = ws + OFF_Y2;
  float* zb = ws + OFF_Z;
  float* c0b = ws + OFF_C0;
  float* klb = ws + OFF_KL;
  float* gall = ws + OFF_GALL;
  float* Wbuf = ws + OFF_WBUF;

  const bool two_phase = (ws_size >= WS_NEED_TWO_PHASE);

  gcn_kernel<<<62, 256, 0, stream>>>(x, adj, eW1, eb1, eW2, eb2, eW3, eb3,
                                     dict_feat, dict_adj, dW1, db1, dW2, db2,
                                     dW3, db3, xe, de);
  x2_kernel<<<8, 256, 0, stream>>>(xe, x2b);
  z_kernel<<<1, 256, 0, stream>>>(xe, mlp_w, mlp_b, mlp2_w, mlp2_b, zb, c0b);
  attn_kernel<<<30, 64, 0, stream>>>(de, zb, c0b, dsb, y2b, klb);
  if (two_phase) {
    sink_kernel<1><<<960, 256, 0, stream>>>(xe, dsb, x2b, y2b, num_node,
                                            dict_nnode, dist_para, Wbuf);
    gd_gemm_kernel<<<120, 64, 0, stream>>>(Wbuf, dist_para, gall);
  } else {
    sink_kernel<0><<<960, 256, 0, stream>>>(xe, dsb, x2b, y2b, num_node,
                                            dict_nnode, dist_para, gall);
  }
  final_kernel<<<32, 256, 0, stream>>>(gall, weight_lamda, fc1_w, fc1_b, fc2_w,
                                       fc2_b, klb, (float*)d_out);
}

// Round 2
// 458.498 us; speedup vs baseline: 1.8586x; 1.8586x over previous
//
#include <hip/hip_runtime.h>
#include <hip/hip_bf16.h>

// Problem constants
// B=32, N=64, D=30, ND=64, F0=64, H1=128, H2=64, H3=32, L=8, SINK_K=10
// LAMDA = {0.01,0.1,0.5,1.0,3.0,5.0,10.0,20.0}, P0=0.5, EPS=1e-6

__device__ __constant__ float c_LAM[8] = {0.01f, 0.1f, 0.5f, 1.0f, 3.0f, 5.0f, 10.0f, 20.0f};

// ---------------- workspace layout (float offsets) ----------------
constexpr int OFF_XE   = 0;         // 32*64*32 = 65536
constexpr int OFF_DE   = 65536;     // 30*64*32 = 61440
constexpr int OFF_DS   = 126976;    // 30*64*32 = 61440
constexpr int OFF_X2   = 188416;    // 2048
constexpr int OFF_Y2   = 190464;    // 1920
constexpr int OFF_Z    = 192384;    // 32
constexpr int OFF_C0   = 192416;    // 16
constexpr int OFF_KL   = 192432;    // 48
constexpr int OFF_GALL = 192480;    // 8*32*960 = 245760
constexpr int OFF_WBUF = 438272;    // 7680*4096 = 31457280  (two-phase only)
constexpr size_t WS_NEED_TWO_PHASE = (size_t)(OFF_WBUF + 7680ull * 4096ull) * 4ull; // 127,582,208 B

// =====================================================================
// GCN encoder: one block per graph (blocks 0..31 = x-encoder, 32..61 = dict)
// =====================================================================
template <int K, int J>
__device__ __forceinline__ void mm64(const float* __restrict__ A, int lda,
                                     const float* __restrict__ W,
                                     float* __restrict__ C,
                                     const float* __restrict__ bias,
                                     bool do_relu, int t) {
  constexpr int JT = J >> 2;        // float4 tiles per row
  constexpr int TILES = 16 * JT;    // 16 i-tiles (64 rows / 4)
  for (int task = t; task < TILES; task += 256) {
    int i4 = task / JT;
    int j4 = task - i4 * JT;
    const float* a0 = A + (i4 * 4 + 0) * lda;
    const float* a1 = a0 + lda;
    const float* a2 = a1 + lda;
    const float* a3 = a2 + lda;
    float acc[4][4];
#pragma unroll
    for (int r = 0; r < 4; ++r)
#pragma unroll
      for (int c = 0; c < 4; ++c) acc[r][c] = 0.0f;
    const float* wp = W + j4 * 4;
#pragma unroll 8
    for (int k = 0; k < K; ++k) {
      float4 w = *(const float4*)(wp + k * J);
      float v0 = a0[k], v1 = a1[k], v2 = a2[k], v3 = a3[k];
      acc[0][0] += v0 * w.x; acc[0][1] += v0 * w.y; acc[0][2] += v0 * w.z; acc[0][3] += v0 * w.w;
      acc[1][0] += v1 * w.x; acc[1][1] += v1 * w.y; acc[1][2] += v1 * w.z; acc[1][3] += v1 * w.w;
      acc[2][0] += v2 * w.x; acc[2][1] += v2 * w.y; acc[2][2] += v2 * w.z; acc[2][3] += v2 * w.w;
      acc[3][0] += v3 * w.x; acc[3][1] += v3 * w.y; acc[3][2] += v3 * w.z; acc[3][3] += v3 * w.w;
    }
    float4 bv = make_float4(0.f, 0.f, 0.f, 0.f);
    if (bias) bv = *(const float4*)(bias + j4 * 4);
#pragma unroll
    for (int r = 0; r < 4; ++r) {
      float o0 = acc[r][0] + bv.x, o1 = acc[r][1] + bv.y;
      float o2 = acc[r][2] + bv.z, o3 = acc[r][3] + bv.w;
      if (do_relu) {
        o0 = fmaxf(o0, 0.f); o1 = fmaxf(o1, 0.f);
        o2 = fmaxf(o2, 0.f); o3 = fmaxf(o3, 0.f);
      }
      float4 st = make_float4(o0, o1, o2, o3);
      *(float4*)(C + (i4 * 4 + r) * J + j4 * 4) = st;
    }
  }
}

__global__ __launch_bounds__(256) void gcn_kernel(
    const float* __restrict__ x, const float* __restrict__ adj,
    const float* __restrict__ eW1, const float* __restrict__ eb1,
    const float* __restrict__ eW2, const float* __restrict__ eb2,
    const float* __restrict__ eW3, const float* __restrict__ eb3,
    const float* __restrict__ dx, const float* __restrict__ dadj,
    const float* __restrict__ dW1, const float* __restrict__ db1,
    const float* __restrict__ dW2, const float* __restrict__ db2,
    const float* __restrict__ dW3, const float* __restrict__ db3,
    float* __restrict__ xe, float* __restrict__ de) {
  __shared__ __align__(16) float C0[64 * 128];
  __shared__ __align__(16) float C1[64 * 128];
  int t = threadIdx.x;
  const float *src, *ad, *W1, *b1, *W2, *b2, *W3, *b3;
  float* outp;
  if (blockIdx.x < 32) {
    int g = blockIdx.x;
    src = x + g * 4096; ad = adj + g * 4096;
    W1 = eW1; b1 = eb1; W2 = eW2; b2 = eb2; W3 = eW3; b3 = eb3;
    outp = xe + g * 2048;
  } else {
    int g = blockIdx.x - 32;
    src = dx + g * 4096; ad = dadj + g * 4096;
    W1 = dW1; b1 = db1; W2 = dW2; b2 = db2; W3 = dW3; b3 = db3;
    outp = de + g * 2048;
  }
  mm64<64, 128>(src, 64, W1, C1, nullptr, false, t);
  __syncthreads();
  mm64<64, 128>(ad, 64, C1, C0, b1, true, t);
  __syncthreads();
  mm64<128, 64>(C0, 128, W2, C1, nullptr, false, t);
  __syncthreads();
  mm64<64, 64>(ad, 64, C1, C0, b2, true, t);
  __syncthreads();
  mm64<64, 32>(C0, 64, W3, C1, nullptr, false, t);
  __syncthreads();
  mm64<64, 32>(ad, 64, C1, outp, b3, false, t);
}

// =====================================================================
__global__ __launch_bounds__(256) void x2_kernel(const float* __restrict__ xe,
                                                 float* __restrict__ x2) {
  int i = blockIdx.x * 256 + threadIdx.x;  // < 2048
  const float* r = xe + i * 32;
  float s = 0.f;
#pragma unroll
  for (int f = 0; f < 32; ++f) s += r[f] * r[f];
  x2[i] = s;
}

// =====================================================================
__global__ __launch_bounds__(256) void z_kernel(
    const float* __restrict__ xe, const float* __restrict__ mlp_w,
    const float* __restrict__ mlp_b, const float* __restrict__ mlp2_w,
    const float* __restrict__ mlp2_b, float* __restrict__ z,
    float* __restrict__ c0) {
  __shared__ float yb[32 * 33];
  int t = threadIdx.x;
  for (int idx = t; idx < 1024; idx += 256) {
    int b = idx >> 5, f = idx & 31;
    float s = 0.f, sb = 0.f;
    for (int n = 0; n < 64; ++n) {
      float v = xe[b * 2048 + n * 32 + f];
      s += v * v;
      sb += v * mlp_w[n];
    }
    yb[b * 33 + f] = sb / (sqrtf(s) + 1e-12f);
  }
  __syncthreads();
  if (t < 32) {
    float zz = 0.f;
    for (int b = 0; b < 32; ++b) zz += yb[b * 33 + t] * mlp2_w[b];
    z[t] = zz;
    if (t == 0) {
      float sm2 = 0.f;
      for (int b = 0; b < 32; ++b) sm2 += mlp2_w[b];
      c0[0] = mlp_b[0] * sm2 + mlp2_b[0];
    }
  }
}

// =====================================================================
// JAX threefry2x32, key = (0, 42)
// =====================================================================
__device__ __forceinline__ unsigned rotl32(unsigned v, int s) {
  return (v << s) | (v >> (32 - s));
}
__device__ __forceinline__ void threefry42(unsigned x0, unsigned x1,
                                           unsigned& o0, unsigned& o1) {
  const unsigned ks0 = 0u, ks1 = 42u, ks2 = 0x1BD11BDAu ^ 0u ^ 42u;
  unsigned ks[3] = {ks0, ks1, ks2};
  x0 += ks[0];
  x1 += ks[1];
  const int R[2][4] = {{13, 15, 26, 6}, {17, 29, 16, 24}};
#pragma unroll
  for (int r = 0; r < 5; ++r) {
    const int* rr = R[r & 1];
#pragma unroll
    for (int i = 0; i < 4; ++i) {
      x0 += x1;
      x1 = rotl32(x1, rr[i]);
      x1 ^= x0;
    }
    x0 += ks[(r + 1) % 3];
    x1 += ks[(r + 2) % 3] + (unsigned)(r + 1);
  }
  o0 = x0;
  o1 = x1;
}

// =====================================================================
__global__ __launch_bounds__(64) void attn_kernel(
    const float* __restrict__ de, const float* __restrict__ z,
    const float* __restrict__ c0, float* __restrict__ dsamp,
    float* __restrict__ y2, float* __restrict__ klpart) {
  int d = blockIdx.x, m = threadIdx.x;
  __shared__ float dn[32];
  if (m < 32) {
    float s = 0.f;
    for (int n = 0; n < 64; ++n) {
      float v = de[d * 2048 + n * 32 + m];
      s += v * v;
    }
    dn[m] = sqrtf(s) + 1e-12f;
  }
  __syncthreads();
  const float* row = de + d * 2048 + m * 32;
  float logit = c0[0], s2 = 0.f;
#pragma unroll 8
  for (int f = 0; f < 32; ++f) {
    float v = row[f];
    logit += (v / dn[f]) * z[f];
    s2 += v * v;
  }
  float attn = 1.0f / (1.0f + expf(-logit));
  int e = d * 64 + m;
  unsigned o0, o1, bits;
  if (e < 960) {
    threefry42((unsigned)e, (unsigned)(960 + e), o0, o1);
    bits = o0;
  } else {
    threefry42((unsigned)(e - 960), (unsigned)e, o0, o1);
    bits = o1;
  }
  float u = __uint_as_float((bits >> 9) | 0x3f800000u) - 1.0f;
  u = fmaxf(u, 0.0f);
  float bern = (u < attn) ? 1.0f : 0.0f;
  float* dr = dsamp + d * 2048 + m * 32;
#pragma unroll 8
  for (int f = 0; f < 32; ++f) dr[f] = bern * row[f];
  y2[e] = bern * s2;
  float klt = attn * logf(2.0f * attn) + (1.0f - attn) * logf(2.0f * (1.0f - attn));
#pragma unroll
  for (int off = 32; off > 0; off >>= 1) klt += __shfl_down(klt, off, 64);
  if (m == 0) klpart[d] = klt;
}

// =====================================================================
// Fused M / exp / Sinkhorn(10) / G-normalize per (b,d) block, 8 lambdas.
// =====================================================================
template <int TWO_PHASE>
__global__ __launch_bounds__(256) void sink_kernel(
    const float* __restrict__ xe, const float* __restrict__ ds,
    const float* __restrict__ x2g, const float* __restrict__ y2g,
    const int* __restrict__ num_node, const int* __restrict__ dict_nnode,
    const float* __restrict__ dp, float* __restrict__ outbuf) {
  constexpr int O_ML = 0;            // 64*65 = 4160
  constexpr int O_KM = 4160;         // 64*67 = 4288 (aliases XE/DS below)
  constexpr int O_XE = 4160;         // 64*33 = 2112
  constexpr int O_DSL = 4160 + 2112; // 64*33 = 2112
  constexpr int O_UI = 8448;
  constexpr int O_VI = 8512;
  constexpr int O_W1 = 8576;
  constexpr int O_W2 = 8640;
  constexpr int O_X2 = 8704;
  constexpr int O_Y2 = 8768;
  constexpr int O_RMIN = 8832;
  constexpr int O_RINV = 8896;
  constexpr int O_SCR = 8960;        // 1056
  __shared__ __align__(16) float sm[10016];
  float* ML = sm + O_ML;
  float* KM = sm + O_KM;

  int t = threadIdx.x;
  int b = blockIdx.x / 30;
  int d = blockIdx.x - b * 30;

  {
    const float* xsrc = xe + b * 2048;
    const float* dsrc = ds + d * 2048;
    for (int i = t; i < 2048; i += 256) {
      int r = i >> 5, c = i & 31;
      sm[O_XE + r * 33 + c] = xsrc[i];
      sm[O_DSL + r * 33 + c] = dsrc[i];
    }
  }
  if (t < 64) {
    int nn = num_node[b], dnn = dict_nnode[d];
    sm[O_W1 + t] = (t < nn) ? 1.0f / (float)nn : 0.0f;
    sm[O_W2 + t] = (t < dnn) ? 1.0f / (float)dnn : 0.0f;
    sm[O_X2 + t] = x2g[b * 64 + t];
    sm[O_Y2 + t] = y2g[d * 64 + t];
  }
  __syncthreads();
  for (int idx = t; idx < 4096; idx += 256) {
    int i = idx >> 6, j = idx & 63;
    const float* xr = sm + O_XE + i * 33;
    const float* dr = sm + O_DSL + j * 33;
    float acc = 0.f;
#pragma unroll
    for (int f = 0; f < 32; ++f) acc += xr[f] * dr[f];
    ML[i * 65 + j] = sm[O_X2 + i] + sm[O_Y2 + j] - 2.0f * acc;
  }
  __syncthreads();

  const int m_ = t & 63;
  const int q_ = t >> 6;

  for (int l = 0; l < 8; ++l) {
    float lam = c_LAM[l];
    for (int idx = t; idx < 4096; idx += 256) {
      int i = idx >> 6, j = idx & 63;
      float kv = 0.0f;
      if (sm[O_W1 + i] > 0.0f && sm[O_W2 + j] > 0.0f)
        kv = __expf(-lam * ML[i * 65 + j]);
      KM[i * 67 + j] = kv;
    }
    if (t < 64) sm[O_UI + t] = 1.0f;
    __syncthreads();

    float kreg[16], kregT[16];
#pragma unroll
    for (int nn = 0; nn < 16; ++nn) {
      kreg[nn] = KM[(q_ * 16 + nn) * 67 + m_];
      kregT[nn] = KM[m_ * 67 + q_ * 16 + nn];
    }

    for (int it = 0; it < 10; ++it) {
      {
        float s = 0.f;
#pragma unroll
        for (int nn = 0; nn < 16; ++nn) s += kreg[nn] * sm[O_UI + q_ * 16 + nn];
        sm[O_SCR + t] = s;
      }
      __syncthreads();
      if (t < 64) {
        float tv = sm[O_SCR + t] + sm[O_SCR + 64 + t] + sm[O_SCR + 128 + t] +
                   sm[O_SCR + 192 + t];
        sm[O_VI + t] = sm[O_W2 + t] / (tv + 1e-6f);
      }
      __syncthreads();
      {
        float s = 0.f;
#pragma unroll
        for (int nn = 0; nn < 16; ++nn) s += kregT[nn] * sm[O_VI + q_ * 16 + nn];
        sm[O_SCR + t] = s;
      }
      __syncthreads();
      if (t < 64) {
        float tu = sm[O_SCR + t] + sm[O_SCR + 64 + t] + sm[O_SCR + 128 + t] +
                   sm[O_SCR + 192 + t];
        sm[O_UI + t] = sm[O_W1 + t] / (tu + 1e-6f);
      }
      __syncthreads();
    }

    {
      float uin = sm[O_UI + m_];
      float mx = -3.402823466e38f, mn = 3.402823466e38f;
#pragma unroll
      for (int nn = 0; nn < 16; ++nn) {
        float g = uin * kregT[nn] * sm[O_VI + q_ * 16 + nn];
        mx = fmaxf(mx, g);
        mn = fminf(mn, g);
      }
      sm[O_SCR + t] = mx;
      sm[O_SCR + 512 + t] = mn;
    }
    __syncthreads();
    if (t < 64) {
      float mx = fmaxf(fmaxf(sm[O_SCR + t], sm[O_SCR + 64 + t]),
                       fmaxf(sm[O_SCR + 128 + t], sm[O_SCR + 192 + t]));
      float mn = fminf(fminf(sm[O_SCR + 512 + t], sm[O_SCR + 576 + t]),
                       fminf(sm[O_SCR + 640 + t], sm[O_SCR + 704 + t]));
      sm[O_RMIN + t] = mn;
      sm[O_RINV + t] = 1.0f / (mx - mn + 1e-6f);
    }
    __syncthreads();

    int row = (l * 32 + b) * 30 + d;
    if (TWO_PHASE) {
      float* wrow = outbuf + (size_t)row * 4096;
      for (int idx = t; idx < 4096; idx += 256) {
        int i = idx >> 6, j = idx & 63;
        float g = sm[O_UI + i] * KM[i * 67 + j] * sm[O_VI + j];
        float gh = (g - sm[O_RMIN + i]) * sm[O_RINV + i];
        wrow[idx] = gh * ML[i * 65 + j];
      }
      __syncthreads();
    } else {
      for (int idx = t; idx < 4096; idx += 256) {
        int i = idx >> 6, j = idx & 63;
        float g = sm[O_UI + i] * KM[i * 67 + j] * sm[O_VI + j];
        float gh = (g - sm[O_RMIN + i]) * sm[O_RINV + i];
        KM[i * 67 + j] = gh * ML[i * 65 + j];
      }
      __syncthreads();
      {
        int k4 = t & 7, q = t >> 3;
        const float4* dp4 = (const float4*)dp;
        float4 acc = make_float4(0.f, 0.f, 0.f, 0.f);
        int p0 = q * 128;
        for (int pp = 0; pp < 128; ++pp) {
          int p = p0 + pp;
          float w = KM[(p >> 6) * 67 + (p & 63)];
          float4 dv = dp4[p * 8 + k4];
          acc.x += w * dv.x;
          acc.y += w * dv.y;
          acc.z += w * dv.z;
          acc.w += w * dv.w;
        }
        sm[O_SCR + (k4 * 4 + 0) * 33 + q] = acc.x;
        sm[O_SCR + (k4 * 4 + 1) * 33 + q] = acc.y;
        sm[O_SCR + (k4 * 4 + 2) * 33 + q] = acc.z;
        sm[O_SCR + (k4 * 4 + 3) * 33 + q] = acc.w;
      }
      __syncthreads();
      if (t < 32) {
        float s = 0.f;
#pragma unroll
        for (int q2 = 0; q2 < 32; ++q2) s += sm[O_SCR + t * 33 + q2];
        outbuf[(size_t)row * 32 + t] = s;
      }
      __syncthreads();
    }
  }
}

// =====================================================================
// Phase 2: gall(7680x32) = Wbuf(7680x4096) @ dp(4096x32)
// REWRITE: 960 blocks x 256 threads, 8 rows/block.
// Thread layout: kg = t>>3 in [0,32) (k-slice of 128), col4 = t&7 (float4 col).
// Each dp element is read exactly once per block; W rows stream through L1.
// Reduce across kg: 3 wave shuffles (8 kg per wave) + LDS pass over 4 waves.
// =====================================================================
__global__ __launch_bounds__(256) void gd_gemm_kernel(
    const float* __restrict__ Wbuf, const float* __restrict__ dp,
    float* __restrict__ gall) {
  __shared__ __align__(16) float4 red[4 * 8 * 8];  // [wave][row][col4]
  int t = threadIdx.x;
  int col4 = t & 7;
  int kg = t >> 3;          // 0..31
  int wv = t >> 6;          // 0..3
  int r0 = blockIdx.x << 3; // 8 rows per block
  const float4* dp4 = (const float4*)dp;
  const float* Wb = Wbuf + (size_t)r0 * 4096;

  float4 acc[8];
#pragma unroll
  for (int r = 0; r < 8; ++r) acc[r] = make_float4(0.f, 0.f, 0.f, 0.f);

  int k0 = kg << 7;  // kg*128
  for (int kk = 0; kk < 128; ++kk) {
    int k = k0 + kk;
    float4 dv = dp4[k * 8 + col4];
#pragma unroll
    for (int r = 0; r < 8; ++r) {
      float w = Wb[r * 4096 + k];
      acc[r].x += w * dv.x;
      acc[r].y += w * dv.y;
      acc[r].z += w * dv.z;
      acc[r].w += w * dv.w;
    }
  }
  // intra-wave reduce across the 8 kg values in this wave (lane stride 8)
#pragma unroll
  for (int off = 32; off >= 8; off >>= 1) {
#pragma unroll
    for (int r = 0; r < 8; ++r) {
      acc[r].x += __shfl_down(acc[r].x, off, 64);
      acc[r].y += __shfl_down(acc[r].y, off, 64);
      acc[r].z += __shfl_down(acc[r].z, off, 64);
      acc[r].w += __shfl_down(acc[r].w, off, 64);
    }
  }
  if ((t & 63) < 8) {
#pragma unroll
    for (int r = 0; r < 8; ++r) red[(wv * 8 + r) * 8 + col4] = acc[r];
  }
  __syncthreads();
  if (t < 64) {
    int r = t >> 3, c4 = t & 7;
    float4 s = red[(0 * 8 + r) * 8 + c4];
    float4 s1 = red[(1 * 8 + r) * 8 + c4];
    float4 s2 = red[(2 * 8 + r) * 8 + c4];
    float4 s3 = red[(3 * 8 + r) * 8 + c4];
    s.x += s1.x + s2.x + s3.x;
    s.y += s1.y + s2.y + s3.y;
    s.z += s1.z + s2.z + s3.z;
    s.w += s1.w + s2.w + s3.w;
    *(float4*)(gall + (size_t)(r0 + r) * 32 + c4 * 4) = s;
  }
}

// =====================================================================
// Final: coeff = softmax_l(gall @ wl), embed, fc1, fc2, kl
// =====================================================================
__global__ __launch_bounds__(256) void final_kernel(
    const float* __restrict__ gall, const float* __restrict__ wl,
    const float* __restrict__ fc1w, const float* __restrict__ fc1b,
    const float* __restrict__ fc2w, const float* __restrict__ fc2b,
    const float* __restrict__ klpart, float* __restrict__ out) {
  int b = blockIdx.x, t = threadIdx.x;
  __shared__ float embedL[960];
  __shared__ float sred[32];
  __shared__ float coeff[8];
  __shared__ float hL[64];
  float part[8] = {0, 0, 0, 0, 0, 0, 0, 0};
  for (int j = t; j < 960; j += 256) {
    float w = wl[j];
#pragma unroll
    for (int l = 0; l < 8; ++l) part[l] += gall[l * 30720 + b * 960 + j] * w;
  }
#pragma unroll
  for (int off = 32; off > 0; off >>= 1) {
#pragma unroll
    for (int l = 0; l < 8; ++l) part[l] += __shfl_down(part[l], off, 64);
  }
  int wv = t >> 6, lane = t & 63;
  if (lane == 0) {
#pragma unroll
    for (int l = 0; l < 8; ++l) sred[l * 4 + wv] = part[l];
  }
  __syncthreads();
  if (t == 0) {
    float s[8], mx = -3.402823466e38f;
#pragma unroll
    for (int l = 0; l < 8; ++l) {
      s[l] = sred[l * 4] + sred[l * 4 + 1] + sred[l * 4 + 2] + sred[l * 4 + 3];
      mx = fmaxf(mx, s[l]);
    }
    float se = 0.f;
#pragma unroll
    for (int l = 0; l < 8; ++l) {
      s[l] = expf(s[l] - mx);
      se += s[l];
    }
#pragma unroll
    for (int l = 0; l < 8; ++l) coeff[l] = s[l] / se;
  }
  __syncthreads();
  for (int j = t; j < 960; j += 256) {
    float e = 0.f;
#pragma unroll
    for (int l = 0; l < 8; ++l) e += gall[l * 30720 + b * 960 + j] * coeff[l];
    embedL[j] = e;
  }
  __syncthreads();
  if (t < 64) {
    float h = fc1b[t];
    for (int j = 0; j < 960; ++j) h += embedL[j] * fc1w[t * 960 + j];
    hL[t] = h;
  }
  __syncthreads();
  if (t < 3) {
    float o = fc2b[t];
#pragma unroll
    for (int j = 0; j < 64; ++j) o += hL[j] * fc2w[t * 64 + j];
    out[b * 3 + t] = o;
  }
  if (b == 0 && t == 4) {
    float kl = 0.f;
    for (int dd = 0; dd < 30; ++dd) kl += klpart[dd];
    out[96] = kl;
  }
}

// =====================================================================
extern "C" void kernel_launch(void* const* d_in, const int* in_sizes, int n_in,
                              void* d_out, int out_size, void* d_ws,
                              size_t ws_size, hipStream_t stream) {
  (void)in_sizes; (void)n_in; (void)out_size;
  const float* x = (const float*)d_in[0];
  const float* adj = (const float*)d_in[1];
  const int* num_node = (const int*)d_in[2];
  const float* dict_feat = (const float*)d_in[3];
  const float* dict_adj = (const float*)d_in[4];
  const int* dict_nnode = (const int*)d_in[5];
  const float* eW1 = (const float*)d_in[6];
  const float* eb1 = (const float*)d_in[7];
  const float* eW2 = (const float*)d_in[8];
  const float* eb2 = (const float*)d_in[9];
  const float* eW3 = (const float*)d_in[10];
  const float* eb3 = (const float*)d_in[11];
  const float* dW1 = (const float*)d_in[12];
  const float* db1 = (const float*)d_in[13];
  const float* dW2 = (const float*)d_in[14];
  const float* db2 = (const float*)d_in[15];
  const float* dW3 = (const float*)d_in[16];
  const float* db3 = (const float*)d_in[17];
  const float* mlp_w = (const float*)d_in[18];
  const float* mlp_b = (const float*)d_in[19];
  const float* mlp2_w = (const float*)d_in[20];
  const float* mlp2_b = (const float*)d_in[21];
  const float* dist_para = (const float*)d_in[22];
  const float* weight_lamda = (const float*)d_in[23];
  const float* fc1_w = (const float*)d_in[24];
  const float* fc1_b = (const float*)d_in[25];
  const float* fc2_w = (const float*)d_in[26];
  const float* fc2_b = (const float*)d_in[27];

  float* ws = (float*)d_ws;
  float* xe = ws + OFF_XE;
  float* de = ws + OFF_DE;
  float* dsb = ws + OFF_DS;
  float* x2b = ws + OFF_X2;
  float* y2b = ws + OFF_Y2;
  float* zb = ws + OFF_Z;
  float* c0b = ws + OFF_C0;
  float* klb = ws + OFF_KL;
  float* gall = ws + OFF_GALL;
  float* Wbuf = ws + OFF_WBUF;

  const bool two_phase = (ws_size >= WS_NEED_TWO_PHASE);

  gcn_kernel<<<62, 256, 0, stream>>>(x, adj, eW1, eb1, eW2, eb2, eW3, eb3,
                                     dict_feat, dict_adj, dW1, db1, dW2, db2,
                                     dW3, db3, xe, de);
  x2_kernel<<<8, 256, 0, stream>>>(xe, x2b);
  z_kernel<<<1, 256, 0, stream>>>(xe, mlp_w, mlp_b, mlp2_w, mlp2_b, zb, c0b);
  attn_kernel<<<30, 64, 0, stream>>>(de, zb, c0b, dsb, y2b, klb);
  if (two_phase) {
    sink_kernel<1><<<960, 256, 0, stream>>>(xe, dsb, x2b, y2b, num_node,
                                            dict_nnode, dist_para, Wbuf);
    gd_gemm_kernel<<<960, 256, 0, stream>>>(Wbuf, dist_para, gall);
  } else {
    sink_kernel<0><<<960, 256, 0, stream>>>(xe, dsb, x2b, y2b, num_node,
                                            dict_nnode, dist_para, gall);
  }
  final_kernel<<<32, 256, 0, stream>>>(gall, weight_lamda, fc1_w, fc1_b, fc2_w,
                                       fc2_b, klb, (float*)d_out);
}